// Round 1
// baseline (5129.757 us; speedup 1.0000x reference)
//
#include <hip/hip_runtime.h>
#include <math.h>

// FNO forward on gfx950. Spectral conv done as truncated partial DFTs
// (only 64 kx-rows x 32 ky-cols of the 264x264 spectrum are live).
//
// Workspace layout (floats):
//   h    [8][64][264][264]          35,684,352   (in-place across layers)
//   F1   [8*64*264][32] cplx         8,650,752   (aliased as H1 after S3)
//   F2   [8][64][64][32] cplx        2,097,152
//   G    [8][64][64][32] cplx        2,097,152
//   TWy  [264][32] cplx                 16,896
//   TWx  [64][264] cplx                 33,792
//   cwT  [4][64][64]                    16,384   (conv_w transposed to [i][o])
//   TWyT [32][264] cplx                 16,896
// total 48,613,376 floats = 194,453,504 bytes

#define FNO_B 8
#define FNO_C 64
#define FNO_HP 264
#define FNO_HW (264 * 264)

__device__ __forceinline__ float gelu_f(float v) {
    return 0.5f * v * (1.0f + erff(v * 0.7071067811865476f));
}

// ---------------------------------------------------------------- init tables
__global__ __launch_bounds__(256) void fno_init(
    float2* __restrict__ TWy, float2* __restrict__ TWyT,
    float2* __restrict__ TWx, float* __restrict__ cwT,
    const float* __restrict__ conv_w) {
    int idx = blockIdx.x * 256 + threadIdx.x;
    const float w0 = 6.283185307179586f / 264.0f;
    if (idx < 8448) {                       // TWy[y][ky] = (cos,sin)(2*pi*y*ky/264)
        int y = idx >> 5, ky = idx & 31;
        int r = (y * ky) % 264;
        float s, c;
        sincosf(w0 * (float)r, &s, &c);
        TWy[idx] = make_float2(c, s);
        TWyT[ky * 264 + y] = make_float2(c, s);
    } else if (idx < 8448 + 16896) {        // TWx[m][x], kx = m<32 ? m : 200+m
        int j = idx - 8448;
        int m = j / 264, x = j - m * 264;
        int kx = (m < 32) ? m : (200 + m);
        int r = (kx * x) % 264;
        float s, c;
        sincosf(w0 * (float)r, &s, &c);
        TWx[j] = make_float2(c, s);
    } else {                                // cwT[k][i][o] = conv_w[k][o][i]
        int j = idx - (8448 + 16896);
        int k = j >> 12, rest = j & 4095;
        int i = rest >> 6, o = rest & 63;
        cwT[j] = conv_w[(k * 64 + o) * 64 + i];
    }
}

// ------------------------------------------------------------------- lift
// h[b][c][x][y] over padded 264x264 domain (zeros in pad region).
__global__ __launch_bounds__(256) void fno_lift(
    const float* __restrict__ xin, const float* __restrict__ w1,
    const float* __restrict__ b1, const float* __restrict__ w2,
    const float* __restrict__ b2, float* __restrict__ h) {
    int bx = blockIdx.x;                 // b*264 + x
    int b = bx / 264, x = bx - b * 264;
    for (int y = threadIdx.x; y < 264; y += 256) {
        int obase = (b * 64) * FNO_HW + x * 264 + y;
        if (x >= 256 || y >= 256) {
            for (int c = 0; c < 64; ++c) h[obase + c * FNO_HW] = 0.0f;
            continue;
        }
        float f0 = xin[((b * 3 + 0) * 256 + x) * 256 + y];
        float f1 = xin[((b * 3 + 1) * 256 + x) * 256 + y];
        float f2 = xin[((b * 3 + 2) * 256 + x) * 256 + y];
        float f3 = (float)x * (1.0f / 255.0f);
        float f4 = (float)y * (1.0f / 255.0f);
        float t[32];
#pragma unroll
        for (int j = 0; j < 32; ++j) {
            const float* wr = w1 + j * 5;
            float s = b1[j] + wr[0] * f0 + wr[1] * f1 + wr[2] * f2 +
                      wr[3] * f3 + wr[4] * f4;
            t[j] = gelu_f(s);
        }
        for (int c = 0; c < 64; ++c) {
            const float* wr = w2 + c * 32;
            float s = b2[c];
#pragma unroll
            for (int j = 0; j < 32; ++j) s += wr[j] * t[j];
            h[obase + c * FNO_HW] = s;
        }
    }
}

// ----------------------------------------------------- S1: forward y-DFT
// F1[row][ky] = sum_y h[row][y] * e^{-2pi i ky y/264},  row = (b,c,x)
__global__ __launch_bounds__(256) void fno_s1(
    const float* __restrict__ h, const float2* __restrict__ TWy,
    float2* __restrict__ F1) {
    __shared__ float rows[2112];         // 8 rows x 264
    int base = blockIdx.x * 2112;
    for (int idx = threadIdx.x; idx < 2112; idx += 256)
        rows[idx] = h[base + idx];
    __syncthreads();
    int r = threadIdx.x >> 5, ky = threadIdx.x & 31;
    const float* rp = rows + r * 264;
    float re = 0.f, im = 0.f;
#pragma unroll 4
    for (int y = 0; y < 264; ++y) {
        float a = rp[y];
        float2 t = TWy[y * 32 + ky];
        re += a * t.x;
        im -= a * t.y;
    }
    F1[(blockIdx.x * 8 + r) * 32 + ky] = make_float2(re, im);
}

// ----------------------------------------------------- S2: forward x-DFT
// F2[b][c][m][ky] = sum_x F1[b][c][x][ky] * e^{-2pi i kx_m x/264}
__global__ __launch_bounds__(256) void fno_s2(
    const float2* __restrict__ F1, const float2* __restrict__ TWx,
    float2* __restrict__ F2) {
    __shared__ float2 fbuf[2112];        // 66 x * 32 ky
    __shared__ float2 twb[4224];         // 64 m * 66 x
    int bc = blockIdx.x;
    int ky = threadIdx.x & 31, mg = threadIdx.x >> 5;
    const float2* F1b = F1 + bc * (264 * 32);
    float2 acc[8];
#pragma unroll
    for (int j = 0; j < 8; ++j) acc[j] = make_float2(0.f, 0.f);
    for (int x0 = 0; x0 < 264; x0 += 66) {
        __syncthreads();
        for (int idx = threadIdx.x; idx < 2112; idx += 256)
            fbuf[idx] = F1b[x0 * 32 + idx];
        for (int idx = threadIdx.x; idx < 4224; idx += 256) {
            int m = idx / 66, xx = idx - m * 66;
            twb[idx] = TWx[m * 264 + x0 + xx];
        }
        __syncthreads();
        for (int xx = 0; xx < 66; ++xx) {
            float2 f = fbuf[xx * 32 + ky];
#pragma unroll
            for (int j = 0; j < 8; ++j) {
                float2 t = twb[(mg * 8 + j) * 66 + xx];   // e^{-i}: (c,-s)
                acc[j].x += f.x * t.x + f.y * t.y;
                acc[j].y += f.y * t.x - f.x * t.y;
            }
        }
    }
#pragma unroll
    for (int j = 0; j < 8; ++j)
        F2[(bc * 64 + mg * 8 + j) * 32 + ky] = acc[j];
}

// ----------------------------------------------------- S3: mode mixing
// G[b][o][m][ky] = sum_i F2[b][i][m][ky] * w[i][o][mloc][ky]
__global__ __launch_bounds__(256) void fno_s3(
    const float2* __restrict__ F2, const float2* __restrict__ w1,
    const float2* __restrict__ w2, float2* __restrict__ G) {
    int bi = blockIdx.x;                 // m*4 + og*2 + bh
    int m = bi >> 2, og = (bi >> 1) & 1, bh = bi & 1;
    int ky = threadIdx.x & 31, slot = threadIdx.x >> 5;
    int o0 = og * 32 + slot * 4;
    int mloc = m & 31;
    const float2* wp = (m < 32) ? w1 : w2;
    __shared__ float2 fch[4096];         // 4 b x 32 i x 32 ky
    float2 acc[4][4];
#pragma unroll
    for (int jb = 0; jb < 4; ++jb)
#pragma unroll
        for (int j = 0; j < 4; ++j) acc[jb][j] = make_float2(0.f, 0.f);
    for (int i0 = 0; i0 < 64; i0 += 32) {
        __syncthreads();
        for (int idx = threadIdx.x; idx < 4096; idx += 256) {
            int b_l = idx >> 10, i_l = (idx >> 5) & 31, kk = idx & 31;
            fch[idx] = F2[(((bh * 4 + b_l) * 64 + i0 + i_l) * 64 + m) * 32 + kk];
        }
        __syncthreads();
        for (int ii = 0; ii < 32; ++ii) {
            int i = i0 + ii;
            float2 f[4];
#pragma unroll
            for (int jb = 0; jb < 4; ++jb) f[jb] = fch[(jb * 32 + ii) * 32 + ky];
#pragma unroll
            for (int j = 0; j < 4; ++j) {
                float2 w = wp[((i * 64 + o0 + j) * 32 + mloc) * 32 + ky];
#pragma unroll
                for (int jb = 0; jb < 4; ++jb) {
                    acc[jb][j].x += f[jb].x * w.x - f[jb].y * w.y;
                    acc[jb][j].y += f[jb].x * w.y + f[jb].y * w.x;
                }
            }
        }
    }
#pragma unroll
    for (int jb = 0; jb < 4; ++jb)
#pragma unroll
        for (int j = 0; j < 4; ++j)
            G[(((bh * 4 + jb) * 64 + o0 + j) * 64 + m) * 32 + ky] = acc[jb][j];
}

// ----------------------------------------------------- S4: inverse x-DFT
// H1[b][o][x][ky] = scale_ky * sum_m G[b][o][m][ky] * e^{+2pi i kx_m x/264}
__global__ __launch_bounds__(256) void fno_s4(
    const float2* __restrict__ G, const float2* __restrict__ TWx,
    float2* __restrict__ H1) {
    __shared__ float2 g[2048];
    __shared__ float2 twc[512];
    int bo = blockIdx.x;
    for (int idx = threadIdx.x; idx < 2048; idx += 256)
        g[idx] = G[bo * 2048 + idx];
    int ky = threadIdx.x & 31, xs = threadIdx.x >> 5;
    float scale = (ky == 0 ? 1.0f : 2.0f) * (1.0f / (264.0f * 264.0f));
    for (int xb = 0; xb < 264; xb += 8) {
        __syncthreads();
        for (int idx = threadIdx.x; idx < 512; idx += 256) {
            int m = idx >> 3, xx = idx & 7;
            twc[idx] = TWx[m * 264 + xb + xx];
        }
        __syncthreads();
        int x = xb + xs;
        float re = 0.f, im = 0.f;
#pragma unroll 8
        for (int mm = 0; mm < 64; ++mm) {
            float2 gg = g[mm * 32 + ky];
            float2 t = twc[mm * 8 + xs];  // e^{+i}: (c,s)
            re += gg.x * t.x - gg.y * t.y;
            im += gg.x * t.y + gg.y * t.x;
        }
        H1[(bo * 264 + x) * 32 + ky] = make_float2(re * scale, im * scale);
    }
}

// ---------------------------- S5: fused 1x1 conv + inverse y-DFT + bias + GELU
// out[b][o][x][y] = act( cb[o] + sum_i cw[o][i] h[b][i][x][y]
//                        + sum_ky Re(H1[b][o][x][ky] e^{+2pi i ky y/264}) )
// In-place on h for layers 0..2; layer 3 writes cropped fp32 to d_out.
template <int LAST>
__global__ __launch_bounds__(320) void fno_s5(
    const float* hin, const float2* __restrict__ H1,
    const float2* __restrict__ TWyT, const float* __restrict__ cwT,
    const float* __restrict__ cb, float* out) {
    int bx = blockIdx.x;                 // b*264 + x
    int b = bx / 264, x = bx - b * 264;
    if (LAST && x >= 256) return;
    __shared__ float hbuf[16 * 264];
    __shared__ float2 h1buf[2048];
    int tid = threadIdx.x;
    for (int idx = tid; idx < 2048; idx += 320)
        h1buf[idx] = H1[((b * 64 + (idx >> 5)) * 264 + x) * 32 + (idx & 31)];
    int y = tid;
    bool act = (y < 264);
    float acc[64];
#pragma unroll
    for (int o = 0; o < 64; ++o) acc[o] = cb[o];
    for (int i0 = 0; i0 < 64; i0 += 16) {
        __syncthreads();
        for (int idx = tid; idx < 16 * 264; idx += 320) {
            int il = idx / 264, yy = idx - il * 264;
            hbuf[idx] = hin[(b * 64 + i0 + il) * FNO_HW + x * 264 + yy];
        }
        __syncthreads();
        if (act) {
            for (int ii = 0; ii < 16; ++ii) {
                float a = hbuf[ii * 264 + y];
                const float* cwr = cwT + (i0 + ii) * 64;
#pragma unroll
                for (int o = 0; o < 64; ++o) acc[o] += cwr[o] * a;
            }
        }
    }
    if (act) {
        for (int ky = 0; ky < 32; ++ky) {
            float2 t = TWyT[ky * 264 + y];
#pragma unroll
            for (int o = 0; o < 64; ++o) {
                float2 hh = h1buf[o * 32 + ky];
                acc[o] += hh.x * t.x - hh.y * t.y;
            }
        }
        if (LAST) {
            if (y < 256) {
                for (int o = 0; o < 64; ++o)
                    out[((b * 64 + o) * 256 + x) * 256 + y] = acc[o];
            }
        } else {
            for (int o = 0; o < 64; ++o)
                out[((b * 64 + o) * 264 + x) * 264 + y] = gelu_f(acc[o]);
        }
    }
}

// --------------------------------------------------------------------- launch
extern "C" void kernel_launch(void* const* d_in, const int* in_sizes, int n_in,
                              void* d_out, int out_size, void* d_ws,
                              size_t ws_size, hipStream_t stream) {
    const float* x   = (const float*)d_in[0];
    const float* lw1 = (const float*)d_in[1];
    const float* lb1 = (const float*)d_in[2];
    const float* lw2 = (const float*)d_in[3];
    const float* lb2 = (const float*)d_in[4];
    const float* cw  = (const float*)d_in[5];
    const float* cb  = (const float*)d_in[6];
    const float* sw1 = (const float*)d_in[7];
    const float* sw2 = (const float*)d_in[8];

    if (ws_size < 194453504ull) return;  // workspace layout requires ~185.5 MiB

    float*  ws   = (float*)d_ws;
    float*  h    = ws;
    float2* F1   = (float2*)(ws + 35684352);
    float2* F2   = (float2*)(ws + 44335104);
    float2* G    = (float2*)(ws + 46432256);
    float2* TWy  = (float2*)(ws + 48529408);
    float2* TWx  = (float2*)(ws + 48546304);
    float*  cwT  = ws + 48580096;
    float2* TWyT = (float2*)(ws + 48596480);
    float2* H1   = F1;                   // F1 dead after S2; reuse for H1

    fno_init<<<163, 256, 0, stream>>>(TWy, TWyT, TWx, cwT, cw);
    fno_lift<<<2112, 256, 0, stream>>>(x, lw1, lb1, lw2, lb2, h);
    for (int k = 0; k < 4; ++k) {
        fno_s1<<<16896, 256, 0, stream>>>(h, TWy, F1);
        fno_s2<<<512, 256, 0, stream>>>(F1, TWx, F2);
        fno_s3<<<256, 256, 0, stream>>>(
            F2, (const float2*)sw1 + (size_t)k * 4194304,
            (const float2*)sw2 + (size_t)k * 4194304, G);
        fno_s4<<<512, 256, 0, stream>>>(G, TWx, H1);
        const float* cwTk = cwT + k * 4096;
        const float* cbk  = cb + k * 64;
        if (k < 3)
            fno_s5<0><<<2112, 320, 0, stream>>>(h, H1, TWyT, cwTk, cbk, h);
        else
            fno_s5<1><<<2112, 320, 0, stream>>>(h, H1, TWyT, cwTk, cbk,
                                                (float*)d_out);
    }
}

// Round 2
// 2546.083 us; speedup vs baseline: 2.0148x; 2.0148x over previous
//
#include <hip/hip_runtime.h>
#include <math.h>

// FNO forward on gfx950. Spectral conv done as truncated partial DFTs
// (only 64 kx-rows x 32 ky-cols of the 264x264 spectrum are live).
//
// Workspace layout (floats):
//   h    [8][64][264][264]          35,684,352   (in-place across layers)
//   F1   [8*64*264][32] cplx         8,650,752   (aliased as H1 after S3)
//   F2   [8][64][64][32] cplx        2,097,152
//   G    [8][64][64][32] cplx        2,097,152
//   TWy  [264][32] cplx                 16,896
//   TWx  [64][264] cplx                 33,792
//   cwT  [4][64][64]                    16,384   (conv_w transposed to [i][o])
//   TA   [64][264]                      16,896   (y-IDFT twiddles as A-rows)
// total 48,613,376 floats = 194,453,504 bytes

#define FNO_HW (264 * 264)

__device__ __forceinline__ float gelu_f(float v) {
    return 0.5f * v * (1.0f + erff(v * 0.7071067811865476f));
}

// ---------------------------------------------------------------- init tables
__global__ __launch_bounds__(256) void fno_init(
    float2* __restrict__ TWy, float* __restrict__ TA,
    float2* __restrict__ TWx, float* __restrict__ cwT,
    const float* __restrict__ conv_w) {
    int idx = blockIdx.x * 256 + threadIdx.x;
    const float w0 = 6.283185307179586f / 264.0f;
    if (idx < 8448) {                       // TWy[y][ky] = (cos,sin)(2*pi*y*ky/264)
        int y = idx >> 5, ky = idx & 31;
        int r = (y * ky) % 264;
        float s, c;
        sincosf(w0 * (float)r, &s, &c);
        TWy[idx] = make_float2(c, s);
        TA[(2 * ky) * 264 + y] = c;          // A-row layout for s5 GEMM
        TA[(2 * ky + 1) * 264 + y] = s;
    } else if (idx < 8448 + 16896) {        // TWx[m][x], kx = m<32 ? m : 200+m
        int j = idx - 8448;
        int m = j / 264, x = j - m * 264;
        int kx = (m < 32) ? m : (200 + m);
        int r = (kx * x) % 264;
        float s, c;
        sincosf(w0 * (float)r, &s, &c);
        TWx[j] = make_float2(c, s);
    } else {                                // cwT[k][i][o] = conv_w[k][o][i]
        int j = idx - (8448 + 16896);
        int k = j >> 12, rest = j & 4095;
        int i = rest >> 6, o = rest & 63;
        cwT[j] = conv_w[(k * 64 + o) * 64 + i];
    }
}

// ------------------------------------------------------------------- lift
__global__ __launch_bounds__(256) void fno_lift(
    const float* __restrict__ xin, const float* __restrict__ w1,
    const float* __restrict__ b1, const float* __restrict__ w2,
    const float* __restrict__ b2, float* __restrict__ h) {
    int bx = blockIdx.x;                 // b*264 + x
    int b = bx / 264, x = bx - b * 264;
    for (int y = threadIdx.x; y < 264; y += 256) {
        int obase = (b * 64) * FNO_HW + x * 264 + y;
        if (x >= 256 || y >= 256) {
            for (int c = 0; c < 64; ++c) h[obase + c * FNO_HW] = 0.0f;
            continue;
        }
        float f0 = xin[((b * 3 + 0) * 256 + x) * 256 + y];
        float f1 = xin[((b * 3 + 1) * 256 + x) * 256 + y];
        float f2 = xin[((b * 3 + 2) * 256 + x) * 256 + y];
        float f3 = (float)x * (1.0f / 255.0f);
        float f4 = (float)y * (1.0f / 255.0f);
        float t[32];
#pragma unroll
        for (int j = 0; j < 32; ++j) {
            const float* wr = w1 + j * 5;
            float s = b1[j] + wr[0] * f0 + wr[1] * f1 + wr[2] * f2 +
                      wr[3] * f3 + wr[4] * f4;
            t[j] = gelu_f(s);
        }
        for (int c = 0; c < 64; ++c) {
            const float* wr = w2 + c * 32;
            float s = b2[c];
#pragma unroll
            for (int j = 0; j < 32; ++j) s += wr[j] * t[j];
            h[obase + c * FNO_HW] = s;
        }
    }
}

// ----------------------------------------------------- S1: forward y-DFT
// F1[R][ky] = sum_y h[R][y] * e^{-2pi i ky y/264},  R = (b,c,x) flat.
// Register-tiled GEMM: block = 128 rows, thread = 4 rows x 4 cplx ky.
__global__ __launch_bounds__(256, 4) void fno_s1(
    const float* __restrict__ h, const float* __restrict__ TWy,
    float* __restrict__ F1) {
    __shared__ float As[44 * 128];       // [y_local][row] transposed
    __shared__ float Ts[44 * 64];        // [y_local][ky] interleaved re/im
    const int tid = threadIdx.x;
    const int rg = tid >> 3, kg = tid & 7;   // rg 0..31 (4 rows), kg 0..7 (4 ky)
    const long long R0 = (long long)blockIdx.x * 128;
    float accr[4][4], acci[4][4];
#pragma unroll
    for (int j = 0; j < 4; ++j)
#pragma unroll
        for (int q = 0; q < 4; ++q) { accr[j][q] = 0.f; acci[j][q] = 0.f; }

    for (int c = 0; c < 6; ++c) {
        const int y0 = c * 44;
        __syncthreads();
        for (int idx = tid; idx < 128 * 11; idx += 256) {
            int r = idx / 11, q = idx - r * 11;
            float4 v = *(const float4*)(h + (R0 + r) * 264 + y0 + q * 4);
            As[(q * 4 + 0) * 128 + r] = v.x;
            As[(q * 4 + 1) * 128 + r] = v.y;
            As[(q * 4 + 2) * 128 + r] = v.z;
            As[(q * 4 + 3) * 128 + r] = v.w;
        }
        for (int idx = tid; idx < 44 * 16; idx += 256) {
            int yl = idx >> 4, q = idx & 15;
            *(float4*)(Ts + yl * 64 + q * 4) =
                *(const float4*)(TWy + (y0 + yl) * 64 + q * 4);
        }
        __syncthreads();
#pragma unroll 4
        for (int yl = 0; yl < 44; ++yl) {
            float4 a  = *(const float4*)(As + yl * 128 + rg * 4);
            float4 t0 = *(const float4*)(Ts + yl * 64 + kg * 8);
            float4 t1 = *(const float4*)(Ts + yl * 64 + kg * 8 + 4);
            float av[4] = {a.x, a.y, a.z, a.w};
            float tc[4] = {t0.x, t0.z, t1.x, t1.z};
            float ts[4] = {t0.y, t0.w, t1.y, t1.w};
#pragma unroll
            for (int j = 0; j < 4; ++j)
#pragma unroll
                for (int q = 0; q < 4; ++q) {
                    accr[j][q] += av[j] * tc[q];
                    acci[j][q] -= av[j] * ts[q];
                }
        }
    }
#pragma unroll
    for (int j = 0; j < 4; ++j) {
        long long R = R0 + rg * 4 + j;
        float4 s0 = {accr[j][0], acci[j][0], accr[j][1], acci[j][1]};
        float4 s1 = {accr[j][2], acci[j][2], accr[j][3], acci[j][3]};
        *(float4*)(F1 + R * 64 + kg * 8) = s0;
        *(float4*)(F1 + R * 64 + kg * 8 + 4) = s1;
    }
}

// ----------------------------------------------------- S2: forward x-DFT
__global__ __launch_bounds__(256) void fno_s2(
    const float2* __restrict__ F1, const float2* __restrict__ TWx,
    float2* __restrict__ F2) {
    __shared__ float2 fbuf[2112];
    __shared__ float2 twb[4224];
    int bc = blockIdx.x;
    int ky = threadIdx.x & 31, mg = threadIdx.x >> 5;
    const float2* F1b = F1 + bc * (264 * 32);
    float2 acc[8];
#pragma unroll
    for (int j = 0; j < 8; ++j) acc[j] = make_float2(0.f, 0.f);
    for (int x0 = 0; x0 < 264; x0 += 66) {
        __syncthreads();
        for (int idx = threadIdx.x; idx < 2112; idx += 256)
            fbuf[idx] = F1b[x0 * 32 + idx];
        for (int idx = threadIdx.x; idx < 4224; idx += 256) {
            int m = idx / 66, xx = idx - m * 66;
            twb[idx] = TWx[m * 264 + x0 + xx];
        }
        __syncthreads();
        for (int xx = 0; xx < 66; ++xx) {
            float2 f = fbuf[xx * 32 + ky];
#pragma unroll
            for (int j = 0; j < 8; ++j) {
                float2 t = twb[(mg * 8 + j) * 66 + xx];
                acc[j].x += f.x * t.x + f.y * t.y;
                acc[j].y += f.y * t.x - f.x * t.y;
            }
        }
    }
#pragma unroll
    for (int j = 0; j < 8; ++j)
        F2[(bc * 64 + mg * 8 + j) * 32 + ky] = acc[j];
}

// ----------------------------------------------------- S3: mode mixing
__global__ __launch_bounds__(256) void fno_s3(
    const float2* __restrict__ F2, const float2* __restrict__ w1,
    const float2* __restrict__ w2, float2* __restrict__ G) {
    int bi = blockIdx.x;
    int m = bi >> 2, og = (bi >> 1) & 1, bh = bi & 1;
    int ky = threadIdx.x & 31, slot = threadIdx.x >> 5;
    int o0 = og * 32 + slot * 4;
    int mloc = m & 31;
    const float2* wp = (m < 32) ? w1 : w2;
    __shared__ float2 fch[4096];
    float2 acc[4][4];
#pragma unroll
    for (int jb = 0; jb < 4; ++jb)
#pragma unroll
        for (int j = 0; j < 4; ++j) acc[jb][j] = make_float2(0.f, 0.f);
    for (int i0 = 0; i0 < 64; i0 += 32) {
        __syncthreads();
        for (int idx = threadIdx.x; idx < 4096; idx += 256) {
            int b_l = idx >> 10, i_l = (idx >> 5) & 31, kk = idx & 31;
            fch[idx] = F2[(((bh * 4 + b_l) * 64 + i0 + i_l) * 64 + m) * 32 + kk];
        }
        __syncthreads();
        for (int ii = 0; ii < 32; ++ii) {
            int i = i0 + ii;
            float2 f[4];
#pragma unroll
            for (int jb = 0; jb < 4; ++jb) f[jb] = fch[(jb * 32 + ii) * 32 + ky];
#pragma unroll
            for (int j = 0; j < 4; ++j) {
                float2 w = wp[((i * 64 + o0 + j) * 32 + mloc) * 32 + ky];
#pragma unroll
                for (int jb = 0; jb < 4; ++jb) {
                    acc[jb][j].x += f[jb].x * w.x - f[jb].y * w.y;
                    acc[jb][j].y += f[jb].x * w.y + f[jb].y * w.x;
                }
            }
        }
    }
#pragma unroll
    for (int jb = 0; jb < 4; ++jb)
#pragma unroll
        for (int j = 0; j < 4; ++j)
            G[(((bh * 4 + jb) * 64 + o0 + j) * 64 + m) * 32 + ky] = acc[jb][j];
}

// ----------------------------------------------------- S4: inverse x-DFT
// H1[b][x][o][ky] = scale_ky * sum_m G[b][o][m][ky] * e^{+2pi i kx_m x/264}
__global__ __launch_bounds__(256) void fno_s4(
    const float2* __restrict__ G, const float2* __restrict__ TWx,
    float2* __restrict__ H1) {
    __shared__ float2 g[2048];
    __shared__ float2 twc[512];
    int bo = blockIdx.x;
    int b = bo >> 6, o = bo & 63;
    for (int idx = threadIdx.x; idx < 2048; idx += 256)
        g[idx] = G[bo * 2048 + idx];
    int ky = threadIdx.x & 31, xs = threadIdx.x >> 5;
    float scale = (ky == 0 ? 1.0f : 2.0f) * (1.0f / (264.0f * 264.0f));
    for (int xb = 0; xb < 264; xb += 8) {
        __syncthreads();
        for (int idx = threadIdx.x; idx < 512; idx += 256) {
            int m = idx >> 3, xx = idx & 7;
            twc[idx] = TWx[m * 264 + xb + xx];
        }
        __syncthreads();
        int x = xb + xs;
        float re = 0.f, im = 0.f;
#pragma unroll 8
        for (int mm = 0; mm < 64; ++mm) {
            float2 gg = g[mm * 32 + ky];
            float2 t = twc[mm * 8 + xs];
            re += gg.x * t.x - gg.y * t.y;
            im += gg.x * t.y + gg.y * t.x;
        }
        H1[(((long long)b * 264 + x) * 64 + o) * 32 + ky] =
            make_float2(re * scale, im * scale);
    }
}

// ---------------------------- S5: fused GEMM  out[y][o] = sum_k A[k][y]W[k][o]
// K=128: rows 0..63 = conv channels (A from h, W from cwT);
//        rows 64..127 = y-IDFT (A from constant TA, W from H1 with sign).
// Thread tile 8y x 8o, acc[64] in registers. In-place on h; LAST crops.
template <int LAST>
__global__ __launch_bounds__(320, 3) void fno_s5(
    const float* __restrict__ hin, const float2* __restrict__ H1,
    const float* __restrict__ TA, const float* __restrict__ cwT,
    const float* __restrict__ cb, float* __restrict__ out) {
    __shared__ float As[32 * 264];
    __shared__ float Ws[32 * 68];
    int bx = blockIdx.x;
    int b, x;
    if (LAST) { b = bx >> 8; x = bx & 255; }
    else      { b = bx / 264; x = bx - b * 264; }
    const int tid = threadIdx.x;
    const int yc = tid >> 3, oc = tid & 7;
    const int y0 = yc * 8, o0 = oc * 8;
    const bool active = tid < 264;

    float acc[8][8];
    if (active) {
#pragma unroll
        for (int oo = 0; oo < 8; ++oo) {
            float bv = cb[o0 + oo];
#pragma unroll
            for (int yy = 0; yy < 8; ++yy) acc[yy][oo] = bv;
        }
    }
    const float* hbase = hin + (long long)(b * 64) * FNO_HW + x * 264;
    const float2* H1g = H1 + ((long long)b * 264 + x) * (64 * 32);

    for (int c = 0; c < 4; ++c) {
        __syncthreads();
        // ---- stage A chunk (32 k-rows x 264 y)
        {
            const float* src = (c < 2) ? (hbase + (long long)(c * 32) * FNO_HW)
                                       : (TA + (c - 2) * 32 * 264);
            const long long rstride = (c < 2) ? (long long)FNO_HW : 264ll;
            for (int idx = tid; idx < 32 * 66; idx += 320) {
                int kl = idx / 66, q = idx - kl * 66;
                *(float4*)(As + kl * 264 + q * 4) =
                    *(const float4*)(src + kl * rstride + q * 4);
            }
        }
        // ---- stage W chunk (32 k-rows x 64 o, pitch 68)
        if (c < 2) {
            for (int idx = tid; idx < 512; idx += 320) {
                int kl = idx >> 4, q = idx & 15;
                *(float4*)(Ws + kl * 68 + q * 4) =
                    *(const float4*)(cwT + (c * 32 + kl) * 64 + q * 4);
            }
        } else {
            int kyb = (c - 2) * 16;
            for (int idx = tid; idx < 1024; idx += 320) {
                int o = idx >> 4, j = idx & 15;
                float2 hh = H1g[o * 32 + kyb + j];
                Ws[(2 * j) * 68 + o] = hh.x;
                Ws[(2 * j + 1) * 68 + o] = -hh.y;
            }
        }
        __syncthreads();
        if (active) {
#pragma unroll 4
            for (int k = 0; k < 32; ++k) {
                float4 a0 = *(const float4*)(As + k * 264 + y0);
                float4 a1 = *(const float4*)(As + k * 264 + y0 + 4);
                float4 w0 = *(const float4*)(Ws + k * 68 + o0);
                float4 w1 = *(const float4*)(Ws + k * 68 + o0 + 4);
                float av[8] = {a0.x, a0.y, a0.z, a0.w, a1.x, a1.y, a1.z, a1.w};
                float wv[8] = {w0.x, w0.y, w0.z, w0.w, w1.x, w1.y, w1.z, w1.w};
#pragma unroll
                for (int yy = 0; yy < 8; ++yy)
#pragma unroll
                    for (int oo = 0; oo < 8; ++oo)
                        acc[yy][oo] += av[yy] * wv[oo];
            }
        }
    }
    if (!active) return;
    if (LAST) {
        if (y0 >= 256) return;
#pragma unroll
        for (int oo = 0; oo < 8; ++oo) {
            float4 s0 = {acc[0][oo], acc[1][oo], acc[2][oo], acc[3][oo]};
            float4 s1 = {acc[4][oo], acc[5][oo], acc[6][oo], acc[7][oo]};
            float* dst = out + ((long long)(b * 64 + o0 + oo) * 256 + x) * 256 + y0;
            *(float4*)dst = s0;
            *(float4*)(dst + 4) = s1;
        }
    } else {
#pragma unroll
        for (int oo = 0; oo < 8; ++oo) {
            float4 s0 = {gelu_f(acc[0][oo]), gelu_f(acc[1][oo]),
                         gelu_f(acc[2][oo]), gelu_f(acc[3][oo])};
            float4 s1 = {gelu_f(acc[4][oo]), gelu_f(acc[5][oo]),
                         gelu_f(acc[6][oo]), gelu_f(acc[7][oo])};
            float* dst = out + (long long)(b * 64 + o0 + oo) * FNO_HW + x * 264 + y0;
            *(float4*)dst = s0;
            *(float4*)(dst + 4) = s1;
        }
    }
}

// --------------------------------------------------------------------- launch
extern "C" void kernel_launch(void* const* d_in, const int* in_sizes, int n_in,
                              void* d_out, int out_size, void* d_ws,
                              size_t ws_size, hipStream_t stream) {
    const float* x   = (const float*)d_in[0];
    const float* lw1 = (const float*)d_in[1];
    const float* lb1 = (const float*)d_in[2];
    const float* lw2 = (const float*)d_in[3];
    const float* lb2 = (const float*)d_in[4];
    const float* cw  = (const float*)d_in[5];
    const float* cb  = (const float*)d_in[6];
    const float* sw1 = (const float*)d_in[7];
    const float* sw2 = (const float*)d_in[8];

    if (ws_size < 194453504ull) return;

    float*  ws   = (float*)d_ws;
    float*  h    = ws;
    float2* F1   = (float2*)(ws + 35684352);
    float2* F2   = (float2*)(ws + 44335104);
    float2* G    = (float2*)(ws + 46432256);
    float2* TWy  = (float2*)(ws + 48529408);
    float2* TWx  = (float2*)(ws + 48546304);
    float*  cwT  = ws + 48580096;
    float*  TA   = ws + 48596480;        // replaces old TWyT slot (16896 floats)
    float2* H1   = F1;                   // F1 dead after S2; reuse for H1

    fno_init<<<163, 256, 0, stream>>>(TWy, TA, TWx, cwT, cw);
    fno_lift<<<2112, 256, 0, stream>>>(x, lw1, lb1, lw2, lb2, h);
    for (int k = 0; k < 4; ++k) {
        fno_s1<<<1056, 256, 0, stream>>>(h, (const float*)TWy, (float*)F1);
        fno_s2<<<512, 256, 0, stream>>>(F1, TWx, F2);
        fno_s3<<<256, 256, 0, stream>>>(
            F2, (const float2*)sw1 + (size_t)k * 4194304,
            (const float2*)sw2 + (size_t)k * 4194304, G);
        fno_s4<<<512, 256, 0, stream>>>(G, TWx, H1);
        const float* cwTk = cwT + k * 4096;
        const float* cbk  = cb + k * 64;
        if (k < 3)
            fno_s5<0><<<2112, 320, 0, stream>>>(h, H1, TA, cwTk, cbk, h);
        else
            fno_s5<1><<<2048, 320, 0, stream>>>(h, H1, TA, cwTk, cbk,
                                                (float*)d_out);
    }
}